// Round 1
// baseline (750.604 us; speedup 1.0000x reference)
//
#include <hip/hip_runtime.h>
#include <hip/hip_bf16.h>

// Problem constants
#define D_M   512          // d_model
#define H_M   1024         // 2*d
#define G_N   8
#define E_N   8
#define T_N   1024         // BATCH*SEQ
#define NEXP  64           // G*E
#define CAP   1024         // max tokens per (g,e): top-2 experts distinct -> <=1/token

#define BT 64              // token tile
#define BJ 128             // output-column tile
#define KC 32              // K chunk

// ---------------- routing: per-token top2 groups, top2 experts ----------------
__global__ __launch_bounds__(64) void k_route(
    const float* __restrict__ x, const float* __restrict__ g1,
    const float* __restrict__ g2, int* __restrict__ slotGE,
    float* __restrict__ slotW) {
  __shared__ float xs[D_M];
  __shared__ float l2s[G_N][E_N];
  __shared__ float l1s[G_N];
  __shared__ float l1part[G_N][8];
  const int t = blockIdx.x;
  const int lane = threadIdx.x;
  const float* xr = x + (size_t)t * D_M;
  for (int i = lane; i < D_M; i += 64) xs[i] = xr[i];
  __syncthreads();
  // logits2: lane -> (g,e), full 512-dot
  {
    const int g = lane >> 3, e = lane & 7;
    const float* gp = g2 + (size_t)g * D_M * E_N + e;
    float acc = 0.f;
    #pragma unroll 8
    for (int i = 0; i < D_M; i++) acc += xs[i] * gp[(size_t)i * E_N];
    l2s[g][e] = acc;
  }
  // logits1: lane -> (g, k-chunk of 64)
  {
    const int g = lane >> 3, c = lane & 7;
    float acc = 0.f;
    #pragma unroll 8
    for (int i = c * 64; i < c * 64 + 64; i++) acc += xs[i] * g1[(size_t)i * G_N + g];
    l1part[g][c] = acc;
  }
  __syncthreads();
  if (lane < G_N) {
    float s = 0.f;
    #pragma unroll
    for (int c = 0; c < 8; c++) s += l1part[lane][c];
    l1s[lane] = s;
  }
  __syncthreads();
  if (lane == 0) {
    // top2 of l1s (ties -> lower index, matches lax.top_k)
    int a1 = 0;
    for (int g = 1; g < G_N; g++) if (l1s[g] > l1s[a1]) a1 = g;
    int a2 = (a1 == 0) ? 1 : 0;
    for (int g = 0; g < G_N; g++) if (g != a1 && l1s[g] > l1s[a2]) a2 = g;
    const float m = l1s[a1];
    float w1a = __expf(l1s[a1] - m), w1b = __expf(l1s[a2] - m);
    const float inv = 1.f / (w1a + w1b);
    w1a *= inv; w1b *= inv;
    const int gsel[2] = {a1, a2};
    const float wsel[2] = {w1a, w1b};
    for (int a = 0; a < 2; a++) {
      const int g = gsel[a];
      int e1 = 0;
      for (int e = 1; e < E_N; e++) if (l2s[g][e] > l2s[g][e1]) e1 = e;
      int e2 = (e1 == 0) ? 1 : 0;
      for (int e = 0; e < E_N; e++) if (e != e1 && l2s[g][e] > l2s[g][e2]) e2 = e;
      const float mm = l2s[g][e1];
      float ua = __expf(l2s[g][e1] - mm), ub = __expf(l2s[g][e2] - mm);
      const float uin = 1.f / (ua + ub);
      ua *= uin; ub *= uin;
      slotGE[t * 4 + a * 2 + 0] = g * E_N + e1;
      slotW [t * 4 + a * 2 + 0] = wsel[a] * ua;
      slotGE[t * 4 + a * 2 + 1] = g * E_N + e2;
      slotW [t * 4 + a * 2 + 1] = wsel[a] * ub;
    }
  }
}

// ---------------- build per-expert token lists ----------------
__global__ __launch_bounds__(256) void k_build(
    const int* __restrict__ slotGE, int* __restrict__ counts,
    int* __restrict__ list) {
  const int ts = blockIdx.x * 256 + threadIdx.x;
  if (ts >= T_N * 4) return;
  const int ge = slotGE[ts];
  const int pos = atomicAdd(&counts[ge], 1);
  list[ge * CAP + pos] = ts;
}

// ---------------- GEMM1: h = relu(x @ W1 + b1), gathered by expert ----------------
__global__ __launch_bounds__(256) void k_mlp1(
    const float* __restrict__ x, const float* __restrict__ W1,
    const float* __restrict__ b1, const int* __restrict__ counts,
    const int* __restrict__ list, float* __restrict__ h_ws) {
  const int ge = blockIdx.x >> 3;          // 64 experts x 8 col-blocks
  const int j0 = (blockIdx.x & 7) * BJ;
  const int n = counts[ge];
  if (n == 0) return;
  __shared__ float xs[KC][BT];
  __shared__ float ws[KC][BJ];
  __shared__ int tokTS[BT];
  const int tid = threadIdx.x;
  const int tx = tid & 15, ty = tid >> 4;  // tx: 8 cols each, ty: 4 tokens each
  const float* Wp = W1 + (size_t)ge * D_M * H_M + j0;
  float bj[8];
  #pragma unroll
  for (int c = 0; c < 8; c++) bj[c] = b1[ge * H_M + j0 + tx * 8 + c];

  for (int t0 = 0; t0 < n; t0 += BT) {
    __syncthreads();
    if (tid < BT) {
      const int idx = t0 + tid;
      tokTS[tid] = list[ge * CAP + (idx < n ? idx : 0)];
    }
    __syncthreads();
    float acc[4][8];
    #pragma unroll
    for (int r = 0; r < 4; r++)
      #pragma unroll
      for (int c = 0; c < 8; c++) acc[r][c] = 0.f;

    for (int i0 = 0; i0 < D_M; i0 += KC) {
      __syncthreads();
      // stage x rows (transposed to [k][token])
      #pragma unroll
      for (int rep = 0; rep < 2; rep++) {
        const int tt = rep * 32 + (tid >> 3);
        const int kq = (tid & 7) * 4;
        const int tok = tokTS[tt] >> 2;
        const float4 v = *(const float4*)&x[(size_t)tok * D_M + i0 + kq];
        xs[kq + 0][tt] = v.x; xs[kq + 1][tt] = v.y;
        xs[kq + 2][tt] = v.z; xs[kq + 3][tt] = v.w;
      }
      // stage W1 tile [KC][BJ]
      #pragma unroll
      for (int sw = 0; sw < 4; sw++) {
        const int idx = sw * 256 + tid;
        const int kk = idx >> 5;
        const int jj = (idx & 31) * 4;
        *(float4*)&ws[kk][jj] = *(const float4*)&Wp[(size_t)(i0 + kk) * H_M + jj];
      }
      __syncthreads();
      #pragma unroll 8
      for (int k = 0; k < KC; k++) {
        float xv[4], wv[8];
        *(float4*)&xv[0] = *(const float4*)&xs[k][ty * 4];
        *(float4*)&wv[0] = *(const float4*)&ws[k][tx * 8];
        *(float4*)&wv[4] = *(const float4*)&ws[k][tx * 8 + 4];
        #pragma unroll
        for (int r = 0; r < 4; r++)
          #pragma unroll
          for (int c = 0; c < 8; c++) acc[r][c] += xv[r] * wv[c];
      }
    }
    #pragma unroll
    for (int r = 0; r < 4; r++) {
      const int tt = ty * 4 + r;
      if (t0 + tt < n) {
        const int ts = tokTS[tt];
        float* hp = h_ws + (size_t)ts * H_M + j0 + tx * 8;
        #pragma unroll
        for (int c = 0; c < 8; c++) {
          const float v = acc[r][c] + bj[c];
          hp[c] = v > 0.f ? v : 0.f;
        }
      }
    }
  }
}

// ---------------- GEMM2: y = w * (h @ W2 + b2), gathered by expert ----------------
__global__ __launch_bounds__(256) void k_mlp2(
    const float* __restrict__ h_ws, const float* __restrict__ W2,
    const float* __restrict__ b2, const int* __restrict__ counts,
    const int* __restrict__ list, const float* __restrict__ slotW,
    float* __restrict__ y_ws) {
  const int ge = blockIdx.x >> 2;          // 64 experts x 4 col-blocks
  const int j0 = (blockIdx.x & 3) * BJ;
  const int n = counts[ge];
  if (n == 0) return;
  __shared__ float xs[KC][BT];
  __shared__ float ws[KC][BJ];
  __shared__ int tokTS[BT];
  const int tid = threadIdx.x;
  const int tx = tid & 15, ty = tid >> 4;
  const float* Wp = W2 + (size_t)ge * H_M * D_M + j0;
  float bj[8];
  #pragma unroll
  for (int c = 0; c < 8; c++) bj[c] = b2[ge * D_M + j0 + tx * 8 + c];

  for (int t0 = 0; t0 < n; t0 += BT) {
    __syncthreads();
    if (tid < BT) {
      const int idx = t0 + tid;
      tokTS[tid] = list[ge * CAP + (idx < n ? idx : 0)];
    }
    __syncthreads();
    float acc[4][8];
    #pragma unroll
    for (int r = 0; r < 4; r++)
      #pragma unroll
      for (int c = 0; c < 8; c++) acc[r][c] = 0.f;

    for (int i0 = 0; i0 < H_M; i0 += KC) {
      __syncthreads();
      #pragma unroll
      for (int rep = 0; rep < 2; rep++) {
        const int tt = rep * 32 + (tid >> 3);
        const int kq = (tid & 7) * 4;
        const int ts = tokTS[tt];
        const float4 v = *(const float4*)&h_ws[(size_t)ts * H_M + i0 + kq];
        xs[kq + 0][tt] = v.x; xs[kq + 1][tt] = v.y;
        xs[kq + 2][tt] = v.z; xs[kq + 3][tt] = v.w;
      }
      #pragma unroll
      for (int sw = 0; sw < 4; sw++) {
        const int idx = sw * 256 + tid;
        const int kk = idx >> 5;
        const int jj = (idx & 31) * 4;
        *(float4*)&ws[kk][jj] = *(const float4*)&Wp[(size_t)(i0 + kk) * D_M + jj];
      }
      __syncthreads();
      #pragma unroll 8
      for (int k = 0; k < KC; k++) {
        float xv[4], wv[8];
        *(float4*)&xv[0] = *(const float4*)&xs[k][ty * 4];
        *(float4*)&wv[0] = *(const float4*)&ws[k][tx * 8];
        *(float4*)&wv[4] = *(const float4*)&ws[k][tx * 8 + 4];
        #pragma unroll
        for (int r = 0; r < 4; r++)
          #pragma unroll
          for (int c = 0; c < 8; c++) acc[r][c] += xv[r] * wv[c];
      }
    }
    #pragma unroll
    for (int r = 0; r < 4; r++) {
      const int tt = ty * 4 + r;
      if (t0 + tt < n) {
        const int ts = tokTS[tt];
        const float w = slotW[ts];
        float* yp = y_ws + (size_t)ts * D_M + j0 + tx * 8;
        #pragma unroll
        for (int c = 0; c < 8; c++) yp[c] = w * (acc[r][c] + bj[c]);
      }
    }
  }
}

// ---------------- combine 4 slots per token ----------------
__global__ __launch_bounds__(256) void k_combine(
    const float* __restrict__ y_ws, float* __restrict__ out) {
  const int idx = blockIdx.x * 256 + threadIdx.x;   // over T_N*D_M/4 float4s
  if (idx >= T_N * D_M / 4) return;
  const int t = idx >> 7;            // 128 float4 per token
  const int j = (idx & 127) * 4;
  const float* yp = y_ws + (size_t)t * 4 * D_M + j;
  const float4 a = *(const float4*)(yp);
  const float4 b = *(const float4*)(yp + D_M);
  const float4 c = *(const float4*)(yp + 2 * D_M);
  const float4 d = *(const float4*)(yp + 3 * D_M);
  float4 r;
  r.x = a.x + b.x + c.x + d.x;
  r.y = a.y + b.y + c.y + d.y;
  r.z = a.z + b.z + c.z + d.z;
  r.w = a.w + b.w + c.w + d.w;
  *(float4*)&out[(size_t)t * D_M + j] = r;
}

// ---------------- launch ----------------
extern "C" void kernel_launch(void* const* d_in, const int* in_sizes, int n_in,
                              void* d_out, int out_size, void* d_ws, size_t ws_size,
                              hipStream_t stream) {
  const float* x  = (const float*)d_in[0];
  const float* g1 = (const float*)d_in[1];
  const float* g2 = (const float*)d_in[2];
  const float* W1 = (const float*)d_in[3];
  const float* b1 = (const float*)d_in[4];
  const float* W2 = (const float*)d_in[5];
  const float* b2 = (const float*)d_in[6];
  float* out = (float*)d_out;

  char* ws = (char*)d_ws;
  // workspace layout (bytes): needs ~24.5 MB
  int*   slotGE = (int*)(ws + 0);                       // 4096 ints
  float* slotW  = (float*)(ws + 16384);                 // 4096 floats
  int*   counts = (int*)(ws + 32768);                   // 64 ints
  int*   list   = (int*)(ws + 36864);                   // 64*1024 ints (256 KB)
  float* h_ws   = (float*)(ws + 524288);                // 4096*1024 f32 (16 MB)
  float* y_ws   = (float*)(ws + 524288 + 16777216);     // 4096*512 f32 (8 MB)

  hipMemsetAsync(counts, 0, NEXP * sizeof(int), stream);
  k_route<<<T_N, 64, 0, stream>>>(x, g1, g2, slotGE, slotW);
  k_build<<<(T_N * 4) / 256, 256, 0, stream>>>(slotGE, counts, list);
  k_mlp1<<<NEXP * 8, 256, 0, stream>>>(x, W1, b1, counts, list, h_ws);
  k_mlp2<<<NEXP * 4, 256, 0, stream>>>(h_ws, W2, b2, counts, list, slotW, y_ws);
  k_combine<<<(T_N * D_M / 4) / 256, 256, 0, stream>>>(y_ws, out);
}

// Round 2
// 589.475 us; speedup vs baseline: 1.2733x; 1.2733x over previous
//
#include <hip/hip_runtime.h>
#include <hip/hip_bf16.h>

// Problem constants
#define D_M   512          // d_model
#define H_M   1024         // 2*d
#define G_N   8
#define E_N   8
#define T_N   1024         // BATCH*SEQ
#define NEXP  64           // G*E
#define CAP   1024

#define BT 64              // token tile
#define BJ 128             // output-column tile
#define KC 32              // K chunk

// ---------------- routing: per-token top2 groups, top2 experts ----------------
__global__ __launch_bounds__(64) void k_route(
    const float* __restrict__ x, const float* __restrict__ g1,
    const float* __restrict__ g2, int* __restrict__ slotGE,
    float* __restrict__ slotW) {
  __shared__ float xs[D_M];
  __shared__ float l2s[G_N][E_N];
  __shared__ float l1s[G_N];
  __shared__ float l1part[G_N][8];
  const int t = blockIdx.x;
  const int lane = threadIdx.x;
  const float* xr = x + (size_t)t * D_M;
  for (int i = lane; i < D_M; i += 64) xs[i] = xr[i];
  __syncthreads();
  {
    const int g = lane >> 3, e = lane & 7;
    const float* gp = g2 + (size_t)g * D_M * E_N + e;
    float acc = 0.f;
    #pragma unroll 8
    for (int i = 0; i < D_M; i++) acc += xs[i] * gp[(size_t)i * E_N];
    l2s[g][e] = acc;
  }
  {
    const int g = lane >> 3, c = lane & 7;
    float acc = 0.f;
    #pragma unroll 8
    for (int i = c * 64; i < c * 64 + 64; i++) acc += xs[i] * g1[(size_t)i * G_N + g];
    l1part[g][c] = acc;
  }
  __syncthreads();
  if (lane < G_N) {
    float s = 0.f;
    #pragma unroll
    for (int c = 0; c < 8; c++) s += l1part[lane][c];
    l1s[lane] = s;
  }
  __syncthreads();
  if (lane == 0) {
    int a1 = 0;
    for (int g = 1; g < G_N; g++) if (l1s[g] > l1s[a1]) a1 = g;
    int a2 = (a1 == 0) ? 1 : 0;
    for (int g = 0; g < G_N; g++) if (g != a1 && l1s[g] > l1s[a2]) a2 = g;
    const float m = l1s[a1];
    float w1a = __expf(l1s[a1] - m), w1b = __expf(l1s[a2] - m);
    const float inv = 1.f / (w1a + w1b);
    w1a *= inv; w1b *= inv;
    const int gsel[2] = {a1, a2};
    const float wsel[2] = {w1a, w1b};
    for (int a = 0; a < 2; a++) {
      const int g = gsel[a];
      int e1 = 0;
      for (int e = 1; e < E_N; e++) if (l2s[g][e] > l2s[g][e1]) e1 = e;
      int e2 = (e1 == 0) ? 1 : 0;
      for (int e = 0; e < E_N; e++) if (e != e1 && l2s[g][e] > l2s[g][e2]) e2 = e;
      const float mm = l2s[g][e1];
      float ua = __expf(l2s[g][e1] - mm), ub = __expf(l2s[g][e2] - mm);
      const float uin = 1.f / (ua + ub);
      ua *= uin; ub *= uin;
      slotGE[t * 4 + a * 2 + 0] = g * E_N + e1;
      slotW [t * 4 + a * 2 + 0] = wsel[a] * ua;
      slotGE[t * 4 + a * 2 + 1] = g * E_N + e2;
      slotW [t * 4 + a * 2 + 1] = wsel[a] * ub;
    }
  }
}

// ---------------- build per-expert token lists ----------------
__global__ __launch_bounds__(256) void k_build(
    const int* __restrict__ slotGE, int* __restrict__ counts,
    int* __restrict__ list) {
  const int ts = blockIdx.x * 256 + threadIdx.x;
  if (ts >= T_N * 4) return;
  const int ge = slotGE[ts];
  const int pos = atomicAdd(&counts[ge], 1);
  list[ge * CAP + pos] = ts;
}

// ---------------- init h_ws = b1[ge], y_ws = b2[ge] per slot ----------------
__global__ __launch_bounds__(256) void k_init(
    const int* __restrict__ slotGE, const float* __restrict__ b1,
    const float* __restrict__ b2, float* __restrict__ h_ws,
    float* __restrict__ y_ws) {
  const int ts = blockIdx.x;           // 4096 slots
  const int ge = slotGE[ts];
  const int tid = threadIdx.x;
  const float4* b1v = (const float4*)(b1 + (size_t)ge * H_M);
  ((float4*)(h_ws + (size_t)ts * H_M))[tid] = b1v[tid];
  if (tid < D_M / 4) {
    const float4* b2v = (const float4*)(b2 + (size_t)ge * D_M);
    ((float4*)(y_ws + (size_t)ts * D_M))[tid] = b2v[tid];
  }
}

// ---------------- GEMM1 partial: h_ws += x @ W1[ge]  (split-K, atomic) ----------------
__global__ __launch_bounds__(256) void k_mlp1(
    const float* __restrict__ x, const float* __restrict__ W1,
    const int* __restrict__ counts, const int* __restrict__ list,
    float* __restrict__ h_ws) {
  const int b = blockIdx.x;            // 64ge x 8col x 2ksplit = 1024
  const int ge = b >> 4;
  const int cb = (b >> 1) & 7;
  const int ks = b & 1;
  const int j0 = cb * BJ;
  const int k0 = ks * 256;
  const int n = counts[ge];
  if (n == 0) return;
  __shared__ float xs[KC][BT];
  __shared__ float ws[KC][BJ];
  __shared__ int tokTS[BT];
  const int tid = threadIdx.x;
  const int tx = tid & 15, ty = tid >> 4;
  const float* Wp = W1 + (size_t)ge * D_M * H_M + j0;

  for (int t0 = 0; t0 < n; t0 += BT) {
    __syncthreads();
    if (tid < BT) {
      const int idx = t0 + tid;
      tokTS[tid] = list[ge * CAP + (idx < n ? idx : 0)];
    }
    __syncthreads();
    float acc[4][8];
    #pragma unroll
    for (int r = 0; r < 4; r++)
      #pragma unroll
      for (int c = 0; c < 8; c++) acc[r][c] = 0.f;

    for (int i0 = k0; i0 < k0 + 256; i0 += KC) {
      __syncthreads();
      #pragma unroll
      for (int rep = 0; rep < 2; rep++) {
        const int tt = rep * 32 + (tid >> 3);
        const int kq = (tid & 7) * 4;
        const int tok = tokTS[tt] >> 2;
        const float4 v = *(const float4*)&x[(size_t)tok * D_M + i0 + kq];
        xs[kq + 0][tt] = v.x; xs[kq + 1][tt] = v.y;
        xs[kq + 2][tt] = v.z; xs[kq + 3][tt] = v.w;
      }
      #pragma unroll
      for (int sw = 0; sw < 4; sw++) {
        const int idx = sw * 256 + tid;
        const int kk = idx >> 5;
        const int jj = (idx & 31) * 4;
        *(float4*)&ws[kk][jj] = *(const float4*)&Wp[(size_t)(i0 + kk) * H_M + jj];
      }
      __syncthreads();
      #pragma unroll 8
      for (int k = 0; k < KC; k++) {
        float xv[4], wv[8];
        *(float4*)&xv[0] = *(const float4*)&xs[k][ty * 4];
        *(float4*)&wv[0] = *(const float4*)&ws[k][tx * 4];        // cols tx*4..+3
        *(float4*)&wv[4] = *(const float4*)&ws[k][64 + tx * 4];   // cols 64+tx*4..+3
        #pragma unroll
        for (int r = 0; r < 4; r++)
          #pragma unroll
          for (int c = 0; c < 8; c++) acc[r][c] += xv[r] * wv[c];
      }
    }
    #pragma unroll
    for (int r = 0; r < 4; r++) {
      const int tt = ty * 4 + r;
      if (t0 + tt < n) {
        const int ts = tokTS[tt];
        float* hp = h_ws + (size_t)ts * H_M + j0;
        #pragma unroll
        for (int c = 0; c < 4; c++) atomicAdd(&hp[tx * 4 + c], acc[r][c]);
        #pragma unroll
        for (int c = 0; c < 4; c++) atomicAdd(&hp[64 + tx * 4 + c], acc[r][c + 4]);
      }
    }
  }
}

// ---------------- GEMM2 partial: y_ws += relu(h) @ W2[ge]  (split-K, atomic) ----------------
__global__ __launch_bounds__(256) void k_mlp2(
    const float* __restrict__ h_ws, const float* __restrict__ W2,
    const int* __restrict__ counts, const int* __restrict__ list,
    float* __restrict__ y_ws) {
  const int b = blockIdx.x;            // 64ge x 4col x 4ksplit = 1024
  const int ge = b >> 4;
  const int cb = (b >> 2) & 3;
  const int ks = b & 3;
  const int j0 = cb * BJ;
  const int k0 = ks * 256;
  const int n = counts[ge];
  if (n == 0) return;
  __shared__ float xs[KC][BT];
  __shared__ float ws[KC][BJ];
  __shared__ int tokTS[BT];
  const int tid = threadIdx.x;
  const int tx = tid & 15, ty = tid >> 4;
  const float* Wp = W2 + (size_t)ge * H_M * D_M + j0;

  for (int t0 = 0; t0 < n; t0 += BT) {
    __syncthreads();
    if (tid < BT) {
      const int idx = t0 + tid;
      tokTS[tid] = list[ge * CAP + (idx < n ? idx : 0)];
    }
    __syncthreads();
    float acc[4][8];
    #pragma unroll
    for (int r = 0; r < 4; r++)
      #pragma unroll
      for (int c = 0; c < 8; c++) acc[r][c] = 0.f;

    for (int i0 = k0; i0 < k0 + 256; i0 += KC) {
      __syncthreads();
      #pragma unroll
      for (int rep = 0; rep < 2; rep++) {
        const int tt = rep * 32 + (tid >> 3);
        const int kq = (tid & 7) * 4;
        const int ts = tokTS[tt];
        const float4 v = *(const float4*)&h_ws[(size_t)ts * H_M + i0 + kq];
        xs[kq + 0][tt] = fmaxf(v.x, 0.f); xs[kq + 1][tt] = fmaxf(v.y, 0.f);
        xs[kq + 2][tt] = fmaxf(v.z, 0.f); xs[kq + 3][tt] = fmaxf(v.w, 0.f);
      }
      #pragma unroll
      for (int sw = 0; sw < 4; sw++) {
        const int idx = sw * 256 + tid;
        const int kk = idx >> 5;
        const int jj = (idx & 31) * 4;
        *(float4*)&ws[kk][jj] = *(const float4*)&Wp[(size_t)(i0 + kk) * D_M + jj];
      }
      __syncthreads();
      #pragma unroll 8
      for (int k = 0; k < KC; k++) {
        float xv[4], wv[8];
        *(float4*)&xv[0] = *(const float4*)&xs[k][ty * 4];
        *(float4*)&wv[0] = *(const float4*)&ws[k][tx * 4];
        *(float4*)&wv[4] = *(const float4*)&ws[k][64 + tx * 4];
        #pragma unroll
        for (int r = 0; r < 4; r++)
          #pragma unroll
          for (int c = 0; c < 8; c++) acc[r][c] += xv[r] * wv[c];
      }
    }
    #pragma unroll
    for (int r = 0; r < 4; r++) {
      const int tt = ty * 4 + r;
      if (t0 + tt < n) {
        const int ts = tokTS[tt];
        float* yp = y_ws + (size_t)ts * D_M + j0;
        #pragma unroll
        for (int c = 0; c < 4; c++) atomicAdd(&yp[tx * 4 + c], acc[r][c]);
        #pragma unroll
        for (int c = 0; c < 4; c++) atomicAdd(&yp[64 + tx * 4 + c], acc[r][c + 4]);
      }
    }
  }
}

// ---------------- combine: out[t] = sum_s slotW[t,s] * y_ws[t*4+s] ----------------
__global__ __launch_bounds__(256) void k_combine(
    const float* __restrict__ y_ws, const float* __restrict__ slotW,
    float* __restrict__ out) {
  const int idx = blockIdx.x * 256 + threadIdx.x;   // T_N*D_M/4 float4s
  if (idx >= T_N * D_M / 4) return;
  const int t = idx >> 7;
  const int j = (idx & 127) * 4;
  const float w0 = slotW[t * 4 + 0], w1 = slotW[t * 4 + 1];
  const float w2 = slotW[t * 4 + 2], w3 = slotW[t * 4 + 3];
  const float* yp = y_ws + (size_t)t * 4 * D_M + j;
  const float4 a = *(const float4*)(yp);
  const float4 b = *(const float4*)(yp + D_M);
  const float4 c = *(const float4*)(yp + 2 * D_M);
  const float4 d = *(const float4*)(yp + 3 * D_M);
  float4 r;
  r.x = w0 * a.x + w1 * b.x + w2 * c.x + w3 * d.x;
  r.y = w0 * a.y + w1 * b.y + w2 * c.y + w3 * d.y;
  r.z = w0 * a.z + w1 * b.z + w2 * c.z + w3 * d.z;
  r.w = w0 * a.w + w1 * b.w + w2 * c.w + w3 * d.w;
  *(float4*)&out[(size_t)t * D_M + j] = r;
}

// ---------------- launch ----------------
extern "C" void kernel_launch(void* const* d_in, const int* in_sizes, int n_in,
                              void* d_out, int out_size, void* d_ws, size_t ws_size,
                              hipStream_t stream) {
  const float* x  = (const float*)d_in[0];
  const float* g1 = (const float*)d_in[1];
  const float* g2 = (const float*)d_in[2];
  const float* W1 = (const float*)d_in[3];
  const float* b1 = (const float*)d_in[4];
  const float* W2 = (const float*)d_in[5];
  const float* b2 = (const float*)d_in[6];
  float* out = (float*)d_out;

  char* ws = (char*)d_ws;
  int*   slotGE = (int*)(ws + 0);                       // 4096 ints
  float* slotW  = (float*)(ws + 16384);                 // 4096 floats
  int*   counts = (int*)(ws + 32768);                   // 64 ints
  int*   list   = (int*)(ws + 36864);                   // 64*1024 ints
  float* h_ws   = (float*)(ws + 524288);                // 4096*1024 f32 (16 MB)
  float* y_ws   = (float*)(ws + 524288 + 16777216);     // 4096*512 f32 (8 MB)

  hipMemsetAsync(counts, 0, NEXP * sizeof(int), stream);
  k_route<<<T_N, 64, 0, stream>>>(x, g1, g2, slotGE, slotW);
  k_build<<<(T_N * 4) / 256, 256, 0, stream>>>(slotGE, counts, list);
  k_init<<<T_N * 4, 256, 0, stream>>>(slotGE, b1, b2, h_ws, y_ws);
  k_mlp1<<<NEXP * 16, 256, 0, stream>>>(x, W1, counts, list, h_ws);
  k_mlp2<<<NEXP * 16, 256, 0, stream>>>(h_ws, W2, counts, list, y_ws);
  k_combine<<<(T_N * D_M / 4) / 256, 256, 0, stream>>>(y_ws, slotW, out);
}

// Round 3
// 382.537 us; speedup vs baseline: 1.9622x; 1.5410x over previous
//
#include <hip/hip_runtime.h>
#include <hip/hip_bf16.h>

// Problem constants
#define D_M   512
#define H_M   1024
#define G_N   8
#define E_N   8
#define T_N   1024
#define NEXP  64
#define CAP   1024

#define KC    64           // K chunk
#define LDA   72           // LDS row stride (bf16 elems): 64 + 8 pad, keeps 16B align, spreads banks

typedef __attribute__((ext_vector_type(8))) short bf16x8;
typedef __attribute__((ext_vector_type(4))) float f32x4;
typedef __attribute__((ext_vector_type(4))) unsigned int u32x4;

__device__ __forceinline__ unsigned short f2bf(float f) {
  unsigned u = __builtin_bit_cast(unsigned, f);
  u = (u + 0x7fffu + ((u >> 16) & 1u)) >> 16;   // RTN-even
  return (unsigned short)u;
}
__device__ __forceinline__ unsigned pack2(float a, float b) {
  return (unsigned)f2bf(a) | ((unsigned)f2bf(b) << 16);
}

// ---------------- routing: per-token top2 groups, top2 experts (fp32, exact) ----------------
__global__ __launch_bounds__(64) void k_route(
    const float* __restrict__ x, const float* __restrict__ g1,
    const float* __restrict__ g2, int* __restrict__ slotGE,
    float* __restrict__ slotW) {
  __shared__ float xs[D_M];
  __shared__ float l2s[G_N][E_N];
  __shared__ float l1s[G_N];
  __shared__ float l1part[G_N][8];
  const int t = blockIdx.x;
  const int lane = threadIdx.x;
  const float* xr = x + (size_t)t * D_M;
  for (int i = lane; i < D_M; i += 64) xs[i] = xr[i];
  __syncthreads();
  {
    const int g = lane >> 3, e = lane & 7;
    const float* gp = g2 + (size_t)g * D_M * E_N + e;
    float acc = 0.f;
    #pragma unroll 8
    for (int i = 0; i < D_M; i++) acc += xs[i] * gp[(size_t)i * E_N];
    l2s[g][e] = acc;
  }
  {
    const int g = lane >> 3, c = lane & 7;
    float acc = 0.f;
    #pragma unroll 8
    for (int i = c * 64; i < c * 64 + 64; i++) acc += xs[i] * g1[(size_t)i * G_N + g];
    l1part[g][c] = acc;
  }
  __syncthreads();
  if (lane < G_N) {
    float s = 0.f;
    #pragma unroll
    for (int c = 0; c < 8; c++) s += l1part[lane][c];
    l1s[lane] = s;
  }
  __syncthreads();
  if (lane == 0) {
    int a1 = 0;
    for (int g = 1; g < G_N; g++) if (l1s[g] > l1s[a1]) a1 = g;
    int a2 = (a1 == 0) ? 1 : 0;
    for (int g = 0; g < G_N; g++) if (g != a1 && l1s[g] > l1s[a2]) a2 = g;
    const float m = l1s[a1];
    float w1a = __expf(l1s[a1] - m), w1b = __expf(l1s[a2] - m);
    const float inv = 1.f / (w1a + w1b);
    w1a *= inv; w1b *= inv;
    const int gsel[2] = {a1, a2};
    const float wsel[2] = {w1a, w1b};
    for (int a = 0; a < 2; a++) {
      const int g = gsel[a];
      int e1 = 0;
      for (int e = 1; e < E_N; e++) if (l2s[g][e] > l2s[g][e1]) e1 = e;
      int e2 = (e1 == 0) ? 1 : 0;
      for (int e = 0; e < E_N; e++) if (e != e1 && l2s[g][e] > l2s[g][e2]) e2 = e;
      const float mm = l2s[g][e1];
      float ua = __expf(l2s[g][e1] - mm), ub = __expf(l2s[g][e2] - mm);
      const float uin = 1.f / (ua + ub);
      ua *= uin; ub *= uin;
      slotGE[t * 4 + a * 2 + 0] = g * E_N + e1;
      slotW [t * 4 + a * 2 + 0] = wsel[a] * ua;
      slotGE[t * 4 + a * 2 + 1] = g * E_N + e2;
      slotW [t * 4 + a * 2 + 1] = wsel[a] * ub;
    }
  }
}

// ---------------- build per-expert token lists ----------------
__global__ __launch_bounds__(256) void k_build(
    const int* __restrict__ slotGE, int* __restrict__ counts,
    int* __restrict__ list) {
  const int ts = blockIdx.x * 256 + threadIdx.x;
  if (ts >= T_N * 4) return;
  const int ge = slotGE[ts];
  const int pos = atomicAdd(&counts[ge], 1);
  list[ge * CAP + pos] = ts;
}

// ---------------- GEMM1 (MFMA bf16): h = relu(x @ W1 + b1) -> bf16 ----------------
// grid: 64 ge x 16 col-blocks of 64. block: 256 thr = 4 waves; wave = one 16-token M-tile.
__global__ __launch_bounds__(256) void k_mlp1(
    const float* __restrict__ x, const float* __restrict__ W1,
    const float* __restrict__ b1, const int* __restrict__ counts,
    const int* __restrict__ list, unsigned short* __restrict__ h_ws) {
  const int ge = blockIdx.x >> 4;
  const int j0 = (blockIdx.x & 15) * 64;
  const int n = counts[ge];
  if (n == 0) return;
  __shared__ unsigned short xl[64 * LDA];   // [token][k]
  __shared__ unsigned short wl[64 * LDA];   // [j-local][k]  (W^T tile)
  __shared__ int tokTS[64];
  const int tid = threadIdx.x;
  const int lane = tid & 63, wave = tid >> 6;
  const int m16 = lane & 15, quad = lane >> 4;

  // staging roles
  const int jp  = tid & 31;          // W: j-pair (j = 2*jp, 2*jp+1)
  const int wko = (tid >> 5) & 7;    // W: k-octet 0..7
  const int tt  = tid & 63;          // x: token row
  const int xko = tid >> 6;          // x: k-octet base (and +4)

  const float* Wbase = W1 + (size_t)ge * D_M * H_M + j0 + jp * 2;
  float bv[4];
  #pragma unroll
  for (int nt = 0; nt < 4; nt++) bv[nt] = b1[ge * H_M + j0 + nt * 16 + m16];

  for (int t0 = 0; t0 < n; t0 += 64) {
    __syncthreads();
    if (tid < 64) {
      int idx = t0 + tid;
      tokTS[tid] = list[ge * CAP + (idx < n ? idx : 0)];
    }
    __syncthreads();
    const float* xrow = x + (size_t)(tokTS[tt] >> 2) * D_M;

    f32x4 acc[4] = {};        // 4 N-tiles x 4 f32
    float2 wreg[8];
    f32x4  xreg[4];

    // prefetch chunk 0
    {
      const float* wp = Wbase + (size_t)(wko * 8) * H_M;
      #pragma unroll
      for (int r = 0; r < 8; r++) wreg[r] = *(const float2*)(wp + (size_t)r * H_M);
      #pragma unroll
      for (int q = 0; q < 2; q++) {
        const int k = (xko + 4 * q) * 8;
        xreg[2*q+0] = *(const f32x4*)(xrow + k);
        xreg[2*q+1] = *(const f32x4*)(xrow + k + 4);
      }
    }
    #pragma unroll
    for (int c = 0; c < 8; c++) {   // K = 512 = 8 * KC
      __syncthreads();
      // W regs -> LDS transposed, cvt bf16
      {
        u32x4 rlo = { pack2(wreg[0].x, wreg[1].x), pack2(wreg[2].x, wreg[3].x),
                      pack2(wreg[4].x, wreg[5].x), pack2(wreg[6].x, wreg[7].x) };
        u32x4 rhi = { pack2(wreg[0].y, wreg[1].y), pack2(wreg[2].y, wreg[3].y),
                      pack2(wreg[4].y, wreg[5].y), pack2(wreg[6].y, wreg[7].y) };
        *(u32x4*)&wl[(jp * 2 + 0) * LDA + wko * 8] = rlo;
        *(u32x4*)&wl[(jp * 2 + 1) * LDA + wko * 8] = rhi;
      }
      // x regs -> LDS, cvt bf16
      #pragma unroll
      for (int q = 0; q < 2; q++) {
        u32x4 xv = { pack2(xreg[2*q].x, xreg[2*q].y), pack2(xreg[2*q].z, xreg[2*q].w),
                     pack2(xreg[2*q+1].x, xreg[2*q+1].y), pack2(xreg[2*q+1].z, xreg[2*q+1].w) };
        *(u32x4*)&xl[tt * LDA + (xko + 4 * q) * 8] = xv;
      }
      __syncthreads();
      // prefetch chunk c+1 (overlaps compute below)
      if (c < 7) {
        const int k0 = (c + 1) * KC;
        const float* wp = Wbase + (size_t)(k0 + wko * 8) * H_M;
        #pragma unroll
        for (int r = 0; r < 8; r++) wreg[r] = *(const float2*)(wp + (size_t)r * H_M);
        #pragma unroll
        for (int q = 0; q < 2; q++) {
          const int k = k0 + (xko + 4 * q) * 8;
          xreg[2*q+0] = *(const f32x4*)(xrow + k);
          xreg[2*q+1] = *(const f32x4*)(xrow + k + 4);
        }
      }
      // compute: 2 k-halves x 4 N-tiles
      #pragma unroll
      for (int kh = 0; kh < 2; kh++) {
        bf16x8 af = *(bf16x8*)&xl[(wave * 16 + m16) * LDA + kh * 32 + quad * 8];
        #pragma unroll
        for (int nt = 0; nt < 4; nt++) {
          bf16x8 bfr = *(bf16x8*)&wl[(nt * 16 + m16) * LDA + kh * 32 + quad * 8];
          acc[nt] = __builtin_amdgcn_mfma_f32_16x16x32_bf16(af, bfr, acc[nt], 0, 0, 0);
        }
      }
    }
    // epilogue: bias + relu -> bf16 h_ws
    #pragma unroll
    for (int i = 0; i < 4; i++) {
      const int tr = wave * 16 + quad * 4 + i;
      if (t0 + tr < n) {
        const int ts = tokTS[tr];
        unsigned short* hp = h_ws + (size_t)ts * H_M + j0;
        #pragma unroll
        for (int nt = 0; nt < 4; nt++) {
          float v = acc[nt][i] + bv[nt];
          hp[nt * 16 + m16] = f2bf(v > 0.f ? v : 0.f);
        }
      }
    }
  }
}

// ---------------- GEMM2 (MFMA bf16): y = slotW * (h @ W2 + b2) -> fp32 ----------------
// grid: 64 ge x 8 col-blocks of 64. K = 1024 = 16 * KC.
__global__ __launch_bounds__(256) void k_mlp2(
    const unsigned short* __restrict__ h_ws, const float* __restrict__ W2,
    const float* __restrict__ b2, const int* __restrict__ counts,
    const int* __restrict__ list, const float* __restrict__ slotW,
    float* __restrict__ y_ws) {
  const int ge = blockIdx.x >> 3;
  const int j0 = (blockIdx.x & 7) * 64;
  const int n = counts[ge];
  if (n == 0) return;
  __shared__ unsigned short xl[64 * LDA];   // [token][k] (h tile, already bf16)
  __shared__ unsigned short wl[64 * LDA];   // [j-local][k]
  __shared__ int tokTS[64];
  const int tid = threadIdx.x;
  const int lane = tid & 63, wave = tid >> 6;
  const int m16 = lane & 15, quad = lane >> 4;

  const int jp  = tid & 31;
  const int wko = (tid >> 5) & 7;
  const int tt  = tid & 63;
  const int xko = tid >> 6;

  const float* Wbase = W2 + (size_t)ge * H_M * D_M + j0 + jp * 2;
  float bv[4];
  #pragma unroll
  for (int nt = 0; nt < 4; nt++) bv[nt] = b2[ge * D_M + j0 + nt * 16 + m16];

  for (int t0 = 0; t0 < n; t0 += 64) {
    __syncthreads();
    if (tid < 64) {
      int idx = t0 + tid;
      tokTS[tid] = list[ge * CAP + (idx < n ? idx : 0)];
    }
    __syncthreads();
    const unsigned short* hrow = h_ws + (size_t)tokTS[tt] * H_M;

    f32x4 acc[4] = {};
    float2 wreg[8];
    u32x4  hreg[2];

    {
      const float* wp = Wbase + (size_t)(wko * 8) * D_M;
      #pragma unroll
      for (int r = 0; r < 8; r++) wreg[r] = *(const float2*)(wp + (size_t)r * D_M);
      #pragma unroll
      for (int q = 0; q < 2; q++)
        hreg[q] = *(const u32x4*)(hrow + (xko + 4 * q) * 8);
    }
    #pragma unroll
    for (int c = 0; c < 16; c++) {   // K = 1024
      __syncthreads();
      {
        u32x4 rlo = { pack2(wreg[0].x, wreg[1].x), pack2(wreg[2].x, wreg[3].x),
                      pack2(wreg[4].x, wreg[5].x), pack2(wreg[6].x, wreg[7].x) };
        u32x4 rhi = { pack2(wreg[0].y, wreg[1].y), pack2(wreg[2].y, wreg[3].y),
                      pack2(wreg[4].y, wreg[5].y), pack2(wreg[6].y, wreg[7].y) };
        *(u32x4*)&wl[(jp * 2 + 0) * LDA + wko * 8] = rlo;
        *(u32x4*)&wl[(jp * 2 + 1) * LDA + wko * 8] = rhi;
      }
      #pragma unroll
      for (int q = 0; q < 2; q++)
        *(u32x4*)&xl[tt * LDA + (xko + 4 * q) * 8] = hreg[q];
      __syncthreads();
      if (c < 15) {
        const int k0 = (c + 1) * KC;
        const float* wp = Wbase + (size_t)(k0 + wko * 8) * D_M;
        #pragma unroll
        for (int r = 0; r < 8; r++) wreg[r] = *(const float2*)(wp + (size_t)r * D_M);
        #pragma unroll
        for (int q = 0; q < 2; q++)
          hreg[q] = *(const u32x4*)(hrow + k0 + (xko + 4 * q) * 8);
      }
      #pragma unroll
      for (int kh = 0; kh < 2; kh++) {
        bf16x8 af = *(bf16x8*)&xl[(wave * 16 + m16) * LDA + kh * 32 + quad * 8];
        #pragma unroll
        for (int nt = 0; nt < 4; nt++) {
          bf16x8 bfr = *(bf16x8*)&wl[(nt * 16 + m16) * LDA + kh * 32 + quad * 8];
          acc[nt] = __builtin_amdgcn_mfma_f32_16x16x32_bf16(af, bfr, acc[nt], 0, 0, 0);
        }
      }
    }
    // epilogue: y_ws = slotW * (acc + b2)
    #pragma unroll
    for (int i = 0; i < 4; i++) {
      const int tr = wave * 16 + quad * 4 + i;
      if (t0 + tr < n) {
        const int ts = tokTS[tr];
        const float w = slotW[ts];
        float* yp = y_ws + (size_t)ts * D_M + j0;
        #pragma unroll
        for (int nt = 0; nt < 4; nt++)
          yp[nt * 16 + m16] = w * (acc[nt][i] + bv[nt]);
      }
    }
  }
}

// ---------------- combine: out[t] = sum_s y_ws[t*4+s] ----------------
__global__ __launch_bounds__(256) void k_combine(
    const float* __restrict__ y_ws, float* __restrict__ out) {
  const int idx = blockIdx.x * 256 + threadIdx.x;
  if (idx >= T_N * D_M / 4) return;
  const int t = idx >> 7;
  const int j = (idx & 127) * 4;
  const float* yp = y_ws + (size_t)t * 4 * D_M + j;
  const float4 a = *(const float4*)(yp);
  const float4 b = *(const float4*)(yp + D_M);
  const float4 c = *(const float4*)(yp + 2 * D_M);
  const float4 d = *(const float4*)(yp + 3 * D_M);
  float4 r;
  r.x = a.x + b.x + c.x + d.x;
  r.y = a.y + b.y + c.y + d.y;
  r.z = a.z + b.z + c.z + d.z;
  r.w = a.w + b.w + c.w + d.w;
  *(float4*)&out[(size_t)t * D_M + j] = r;
}

// ---------------- launch ----------------
extern "C" void kernel_launch(void* const* d_in, const int* in_sizes, int n_in,
                              void* d_out, int out_size, void* d_ws, size_t ws_size,
                              hipStream_t stream) {
  const float* x  = (const float*)d_in[0];
  const float* g1 = (const float*)d_in[1];
  const float* g2 = (const float*)d_in[2];
  const float* W1 = (const float*)d_in[3];
  const float* b1 = (const float*)d_in[4];
  const float* W2 = (const float*)d_in[5];
  const float* b2 = (const float*)d_in[6];
  float* out = (float*)d_out;

  char* ws = (char*)d_ws;
  int*            slotGE = (int*)(ws + 0);                    // 4096 ints
  float*          slotW  = (float*)(ws + 16384);              // 4096 floats
  int*            counts = (int*)(ws + 32768);                // 64 ints
  int*            list   = (int*)(ws + 36864);                // 64*1024 ints (256 KB)
  unsigned short* h_ws   = (unsigned short*)(ws + 524288);    // 4096*1024 bf16 (8 MB)
  float*          y_ws   = (float*)(ws + 524288 + 8388608);   // 4096*512 f32 (8 MB)

  hipMemsetAsync(counts, 0, NEXP * sizeof(int), stream);
  k_route<<<T_N, 64, 0, stream>>>(x, g1, g2, slotGE, slotW);
  k_build<<<(T_N * 4) / 256, 256, 0, stream>>>(slotGE, counts, list);
  k_mlp1<<<NEXP * 16, 256, 0, stream>>>(x, W1, b1, counts, list, h_ws);
  k_mlp2<<<NEXP * 8, 256, 0, stream>>>(h_ws, W2, b2, counts, list, slotW, y_ws);
  k_combine<<<(T_N * D_M / 4) / 256, 256, 0, stream>>>(y_ws, out);
}

// Round 4
// 374.148 us; speedup vs baseline: 2.0062x; 1.0224x over previous
//
#include <hip/hip_runtime.h>
#include <hip/hip_bf16.h>

// Problem constants
#define D_M   512
#define H_M   1024
#define G_N   8
#define E_N   8
#define T_N   1024
#define NEXP  64
#define CAP   1024

#define LDK   520          // padded K row stride for xl (bf16 elems): 520*2=1040 B, 16B-aligned, banks spread

typedef __attribute__((ext_vector_type(8))) short bf16x8;
typedef __attribute__((ext_vector_type(4))) float f32x4;
typedef __attribute__((ext_vector_type(4))) unsigned int u32x4;

__device__ __forceinline__ unsigned short f2bf(float f) {
  unsigned u = __builtin_bit_cast(unsigned, f);
  u = (u + 0x7fffu + ((u >> 16) & 1u)) >> 16;   // RTN-even
  return (unsigned short)u;
}
__device__ __forceinline__ unsigned pack2(float a, float b) {
  return (unsigned)f2bf(a) | ((unsigned)f2bf(b) << 16);
}

// ---------------- routing (fp32, exact) ----------------
__global__ __launch_bounds__(64) void k_route(
    const float* __restrict__ x, const float* __restrict__ g1,
    const float* __restrict__ g2, int* __restrict__ slotGE,
    float* __restrict__ slotW) {
  __shared__ float xs[D_M];
  __shared__ float l2s[G_N][E_N];
  __shared__ float l1s[G_N];
  __shared__ float l1part[G_N][8];
  const int t = blockIdx.x;
  const int lane = threadIdx.x;
  const float* xr = x + (size_t)t * D_M;
  for (int i = lane; i < D_M; i += 64) xs[i] = xr[i];
  __syncthreads();
  {
    const int g = lane >> 3, e = lane & 7;
    const float* gp = g2 + (size_t)g * D_M * E_N + e;
    float acc = 0.f;
    #pragma unroll 8
    for (int i = 0; i < D_M; i++) acc += xs[i] * gp[(size_t)i * E_N];
    l2s[g][e] = acc;
  }
  {
    const int g = lane >> 3, c = lane & 7;
    float acc = 0.f;
    #pragma unroll 8
    for (int i = c * 64; i < c * 64 + 64; i++) acc += xs[i] * g1[(size_t)i * G_N + g];
    l1part[g][c] = acc;
  }
  __syncthreads();
  if (lane < G_N) {
    float s = 0.f;
    #pragma unroll
    for (int c = 0; c < 8; c++) s += l1part[lane][c];
    l1s[lane] = s;
  }
  __syncthreads();
  if (lane == 0) {
    int a1 = 0;
    for (int g = 1; g < G_N; g++) if (l1s[g] > l1s[a1]) a1 = g;
    int a2 = (a1 == 0) ? 1 : 0;
    for (int g = 0; g < G_N; g++) if (g != a1 && l1s[g] > l1s[a2]) a2 = g;
    const float m = l1s[a1];
    float w1a = __expf(l1s[a1] - m), w1b = __expf(l1s[a2] - m);
    const float inv = 1.f / (w1a + w1b);
    w1a *= inv; w1b *= inv;
    const int gsel[2] = {a1, a2};
    const float wsel[2] = {w1a, w1b};
    for (int a = 0; a < 2; a++) {
      const int g = gsel[a];
      int e1 = 0;
      for (int e = 1; e < E_N; e++) if (l2s[g][e] > l2s[g][e1]) e1 = e;
      int e2 = (e1 == 0) ? 1 : 0;
      for (int e = 0; e < E_N; e++) if (e != e1 && l2s[g][e] > l2s[g][e2]) e2 = e;
      const float mm = l2s[g][e1];
      float ua = __expf(l2s[g][e1] - mm), ub = __expf(l2s[g][e2] - mm);
      const float uin = 1.f / (ua + ub);
      ua *= uin; ub *= uin;
      slotGE[t * 4 + a * 2 + 0] = g * E_N + e1;
      slotW [t * 4 + a * 2 + 0] = wsel[a] * ua;
      slotGE[t * 4 + a * 2 + 1] = g * E_N + e2;
      slotW [t * 4 + a * 2 + 1] = wsel[a] * ub;
    }
  }
}

// ---------------- build per-expert token lists ----------------
__global__ __launch_bounds__(256) void k_build(
    const int* __restrict__ slotGE, int* __restrict__ counts,
    int* __restrict__ list) {
  const int ts = blockIdx.x * 256 + threadIdx.x;
  if (ts >= T_N * 4) return;
  const int ge = slotGE[ts];
  const int pos = atomicAdd(&counts[ge], 1);
  list[ge * CAP + pos] = ts;
}

// ---------------- GEMM1: h = relu(x @ W1 + b1) -> bf16. Barrier-free K-loop ----------------
// grid: 64 ge x 8 j-tiles(128). block 256 = 4 waves; wave owns 32 j (nt=2), all 64 tokens (mt=4).
__global__ __launch_bounds__(256, 2) void k_mlp1(
    const float* __restrict__ x, const float* __restrict__ W1,
    const float* __restrict__ b1, const int* __restrict__ counts,
    const int* __restrict__ list, unsigned short* __restrict__ h_ws) {
  const int ge = blockIdx.x >> 3;
  const int j0 = (blockIdx.x & 7) * 128;
  const int n = counts[ge];
  if (n == 0) return;
  __shared__ unsigned short xl[64 * LDK];   // [token][k] full-K, bf16
  __shared__ int tokTS[64];
  const int tid = threadIdx.x;
  const int lane = tid & 63, wave = tid >> 6;
  const int m16 = lane & 15, quad = lane >> 4;

  const float* Wcol = W1 + (size_t)ge * (D_M * H_M) + j0 + wave * 32 + m16;
  float bv[2];
  #pragma unroll
  for (int nt = 0; nt < 2; nt++) bv[nt] = b1[ge * H_M + j0 + wave * 32 + nt * 16 + m16];

  for (int t0 = 0; t0 < n; t0 += 64) {
    __syncthreads();
    if (tid < 64) {
      int idx = t0 + tid;
      tokTS[tid] = list[ge * CAP + (idx < n ? idx : n - 1)];
    }
    __syncthreads();
    // stage x (fp32 -> bf16) once: thread covers token tid>>2, k-lane (tid&3)*4, 32 reps of 16 floats
    {
      const int trow = tid >> 2;
      const int kb = (tid & 3) * 4;
      const float* xr = x + (size_t)(tokTS[trow] >> 2) * D_M + kb;
      unsigned short* dst = &xl[trow * LDK + kb];
      #pragma unroll 8
      for (int rep = 0; rep < 32; rep++) {
        f32x4 v = *(const f32x4*)(xr + rep * 16);
        uint2 p = { pack2(v.x, v.y), pack2(v.z, v.w) };
        *(uint2*)(dst + rep * 16) = p;
      }
    }
    __syncthreads();

    f32x4 acc[4][2] = {};
    float bcur[2][8], bnxt[2][8];
    #pragma unroll
    for (int nt = 0; nt < 2; nt++)
      #pragma unroll
      for (int i = 0; i < 8; i++)
        bcur[nt][i] = Wcol[(size_t)(quad * 8 + i) * H_M + nt * 16];

    #pragma unroll 4
    for (int s = 0; s < 16; s++) {       // K = 512, no barriers
      if (s < 15) {
        #pragma unroll
        for (int nt = 0; nt < 2; nt++)
          #pragma unroll
          for (int i = 0; i < 8; i++)
            bnxt[nt][i] = Wcol[(size_t)((s + 1) * 32 + quad * 8 + i) * H_M + nt * 16];
      }
      bf16x8 bf[2];
      #pragma unroll
      for (int nt = 0; nt < 2; nt++) {
        u32x4 t = { pack2(bcur[nt][0], bcur[nt][1]), pack2(bcur[nt][2], bcur[nt][3]),
                    pack2(bcur[nt][4], bcur[nt][5]), pack2(bcur[nt][6], bcur[nt][7]) };
        bf[nt] = __builtin_bit_cast(bf16x8, t);
      }
      #pragma unroll
      for (int mt = 0; mt < 4; mt++) {
        bf16x8 af = *(bf16x8*)&xl[(mt * 16 + m16) * LDK + s * 32 + quad * 8];
        acc[mt][0] = __builtin_amdgcn_mfma_f32_16x16x32_bf16(af, bf[0], acc[mt][0], 0, 0, 0);
        acc[mt][1] = __builtin_amdgcn_mfma_f32_16x16x32_bf16(af, bf[1], acc[mt][1], 0, 0, 0);
      }
      #pragma unroll
      for (int nt = 0; nt < 2; nt++)
        #pragma unroll
        for (int i = 0; i < 8; i++) bcur[nt][i] = bnxt[nt][i];
    }
    // epilogue: bias + relu -> bf16
    #pragma unroll
    for (int mt = 0; mt < 4; mt++)
      #pragma unroll
      for (int i = 0; i < 4; i++) {
        const int tr = mt * 16 + quad * 4 + i;
        if (t0 + tr < n) {
          const int ts = tokTS[tr];
          unsigned short* hp = h_ws + (size_t)ts * H_M + j0 + wave * 32 + m16;
          #pragma unroll
          for (int nt = 0; nt < 2; nt++) {
            float v = acc[mt][nt][i] + bv[nt];
            hp[nt * 16] = f2bf(v > 0.f ? v : 0.f);
          }
        }
      }
  }
}

// ---------------- GEMM2: y_part = h @ W2 (+b2 on ks=0) -> fp32, K-split 2, barrier-free ----------------
// grid: 64 ge x 4 j-tiles(128) x 2 ksplit. wave owns 32 j (nt=2), all 64 tokens (mt=4).
__global__ __launch_bounds__(256, 2) void k_mlp2(
    const unsigned short* __restrict__ h_ws, const float* __restrict__ W2,
    const float* __restrict__ b2, const int* __restrict__ counts,
    const int* __restrict__ list, float* __restrict__ y0,
    float* __restrict__ y1) {
  const int ge = blockIdx.x >> 3;
  const int j0 = ((blockIdx.x >> 1) & 3) * 128;
  const int ks = blockIdx.x & 1;
  const int n = counts[ge];
  if (n == 0) return;
  __shared__ unsigned short xl[64 * LDK];   // [token][k-half], bf16
  __shared__ int tokTS[64];
  const int tid = threadIdx.x;
  const int lane = tid & 63, wave = tid >> 6;
  const int m16 = lane & 15, quad = lane >> 4;

  const float* Wcol = W2 + (size_t)ge * (H_M * D_M) + (size_t)(ks * 512) * D_M + j0 + wave * 32 + m16;
  float bv[2];
  #pragma unroll
  for (int nt = 0; nt < 2; nt++)
    bv[nt] = ks == 0 ? b2[ge * D_M + j0 + wave * 32 + nt * 16 + m16] : 0.f;
  float* yk = ks == 0 ? y0 : y1;

  for (int t0 = 0; t0 < n; t0 += 64) {
    __syncthreads();
    if (tid < 64) {
      int idx = t0 + tid;
      tokTS[tid] = list[ge * CAP + (idx < n ? idx : n - 1)];
    }
    __syncthreads();
    // stage h-half (already bf16): thread covers token tid>>2, k-lane (tid&3)*8, 16 reps of 32 elems
    {
      const int trow = tid >> 2;
      const int kb = (tid & 3) * 8;
      const unsigned short* hr = h_ws + (size_t)tokTS[trow] * H_M + ks * 512 + kb;
      unsigned short* dst = &xl[trow * LDK + kb];
      #pragma unroll 8
      for (int rep = 0; rep < 16; rep++)
        *(u32x4*)(dst + rep * 32) = *(const u32x4*)(hr + rep * 32);
    }
    __syncthreads();

    f32x4 acc[4][2] = {};
    float bcur[2][8], bnxt[2][8];
    #pragma unroll
    for (int nt = 0; nt < 2; nt++)
      #pragma unroll
      for (int i = 0; i < 8; i++)
        bcur[nt][i] = Wcol[(size_t)(quad * 8 + i) * D_M + nt * 16];

    #pragma unroll 4
    for (int s = 0; s < 16; s++) {       // K-half = 512
      if (s < 15) {
        #pragma unroll
        for (int nt = 0; nt < 2; nt++)
          #pragma unroll
          for (int i = 0; i < 8; i++)
            bnxt[nt][i] = Wcol[(size_t)((s + 1) * 32 + quad * 8 + i) * D_M + nt * 16];
      }
      bf16x8 bf[2];
      #pragma unroll
      for (int nt = 0; nt < 2; nt++) {
        u32x4 t = { pack2(bcur[nt][0], bcur[nt][1]), pack2(bcur[nt][2], bcur[nt][3]),
                    pack2(bcur[nt][4], bcur[nt][5]), pack2(bcur[nt][6], bcur[nt][7]) };
        bf[nt] = __builtin_bit_cast(bf16x8, t);
      }
      #pragma unroll
      for (int mt = 0; mt < 4; mt++) {
        bf16x8 af = *(bf16x8*)&xl[(mt * 16 + m16) * LDK + s * 32 + quad * 8];
        acc[mt][0] = __builtin_amdgcn_mfma_f32_16x16x32_bf16(af, bf[0], acc[mt][0], 0, 0, 0);
        acc[mt][1] = __builtin_amdgcn_mfma_f32_16x16x32_bf16(af, bf[1], acc[mt][1], 0, 0, 0);
      }
      #pragma unroll
      for (int nt = 0; nt < 2; nt++)
        #pragma unroll
        for (int i = 0; i < 8; i++) bcur[nt][i] = bnxt[nt][i];
    }
    #pragma unroll
    for (int mt = 0; mt < 4; mt++)
      #pragma unroll
      for (int i = 0; i < 4; i++) {
        const int tr = mt * 16 + quad * 4 + i;
        if (t0 + tr < n) {
          const int ts = tokTS[tr];
          float* yp = yk + (size_t)ts * D_M + j0 + wave * 32 + m16;
          #pragma unroll
          for (int nt = 0; nt < 2; nt++)
            yp[nt * 16] = acc[mt][nt][i] + bv[nt];
        }
      }
  }
}

// ---------------- combine: out[t] = sum_s slotW[t,s] * (y0+y1)[t*4+s] ----------------
__global__ __launch_bounds__(256) void k_combine(
    const float* __restrict__ y0, const float* __restrict__ y1,
    const float* __restrict__ slotW, float* __restrict__ out) {
  const int idx = blockIdx.x * 256 + threadIdx.x;
  if (idx >= T_N * D_M / 4) return;
  const int t = idx >> 7;
  const int j = (idx & 127) * 4;
  float4 r = {0.f, 0.f, 0.f, 0.f};
  #pragma unroll
  for (int s = 0; s < 4; s++) {
    const float w = slotW[t * 4 + s];
    const size_t off = (size_t)(t * 4 + s) * D_M + j;
    const float4 a = *(const float4*)(y0 + off);
    const float4 b = *(const float4*)(y1 + off);
    r.x += w * (a.x + b.x);
    r.y += w * (a.y + b.y);
    r.z += w * (a.z + b.z);
    r.w += w * (a.w + b.w);
  }
  *(float4*)&out[(size_t)t * D_M + j] = r;
}

// ---------------- launch ----------------
extern "C" void kernel_launch(void* const* d_in, const int* in_sizes, int n_in,
                              void* d_out, int out_size, void* d_ws, size_t ws_size,
                              hipStream_t stream) {
  const float* x  = (const float*)d_in[0];
  const float* g1 = (const float*)d_in[1];
  const float* g2 = (const float*)d_in[2];
  const float* W1 = (const float*)d_in[3];
  const float* b1 = (const float*)d_in[4];
  const float* W2 = (const float*)d_in[5];
  const float* b2 = (const float*)d_in[6];
  float* out = (float*)d_out;

  char* ws = (char*)d_ws;
  int*            slotGE = (int*)(ws + 0);                     // 4096 ints
  float*          slotW  = (float*)(ws + 16384);               // 4096 floats
  int*            counts = (int*)(ws + 32768);                 // 64 ints
  int*            list   = (int*)(ws + 36864);                 // 64*1024 ints (256 KB)
  unsigned short* h_ws   = (unsigned short*)(ws + 524288);     // 4096*1024 bf16 (8 MB)
  float*          y0     = (float*)(ws + 524288 + 8388608);    // 4096*512 f32 (8 MB)
  float*          y1     = (float*)(ws + 524288 + 16777216);   // 4096*512 f32 (8 MB)

  hipMemsetAsync(counts, 0, NEXP * sizeof(int), stream);
  k_route<<<T_N, 64, 0, stream>>>(x, g1, g2, slotGE, slotW);
  k_build<<<(T_N * 4) / 256, 256, 0, stream>>>(slotGE, counts, list);
  k_mlp1<<<NEXP * 8, 256, 0, stream>>>(x, W1, b1, counts, list, h_ws);
  k_mlp2<<<NEXP * 8, 256, 0, stream>>>(h_ws, W2, b2, counts, list, y0, y1);
  k_combine<<<(T_N * D_M / 4) / 256, 256, 0, stream>>>(y0, y1, slotW, out);
}